// Round 1
// baseline (555.508 us; speedup 1.0000x reference)
//
#include <hip/hip_runtime.h>

#define H 1024
#define W 1024
#define KS 21
#define RAD 10
#define TILE_X 64
#define TILE_Y 64
#define HROWS (TILE_Y + 2 * RAD)  // 84

// jnp 'reflect' (no edge repeat) for indices in [-(W-1), 2W-2]
__device__ __forceinline__ int reflect1024(int i) {
    return 1023 - abs(1023 - abs(i));
}

__global__ __launch_bounds__(256)
void gauss_fused(const float* __restrict__ in, const float* __restrict__ k2d,
                 float* __restrict__ out) {
    __shared__ float hbuf[HROWS][TILE_X];  // 84*64*4 = 21504 B
    __shared__ float rw_s[KS];

    const int tid = threadIdx.x;
    const int tx = tid & 63;   // x within tile
    const int tw = tid >> 6;   // wave id 0..3
    const int x0 = blockIdx.x * TILE_X;
    const int y0 = blockIdx.y * TILE_Y;
    const long long plane = (long long)blockIdx.z * (long long)(H * W);
    const float* inp = in + plane;
    float* outp = out + plane;

    // Extract the separable 1D factor: k2d = outer(r,r), r[i] = k2d[i][c]/sqrt(k2d[c][c])
    if (tid < KS) {
        float c = k2d[RAD * KS + RAD];
        rw_s[tid] = k2d[tid * KS + RAD] / sqrtf(c);
    }
    __syncthreads();

    float w[KS];
#pragma unroll
    for (int j = 0; j < KS; ++j) w[j] = rw_s[j];

    // ---- Phase 1: horizontal 21-tap conv into LDS (rows y0-10 .. y0+73) ----
    const int xb = x0 + tx - RAD;
    for (int kk = 0; kk < HROWS / 4; ++kk) {  // 21 iterations, 4 rows each
        const int row = tw + 4 * kk;
        const int gy = reflect1024(y0 + row - RAD);
        const float* rowp = inp + (long long)gy * W;
        float s = 0.f;
#pragma unroll
        for (int j = 0; j < KS; ++j) {
            const int ix = reflect1024(xb + j);
            s += w[j] * rowp[ix];
        }
        hbuf[row][tx] = s;
    }
    __syncthreads();

    // ---- Phase 2: vertical 21-tap conv, 16 outputs per thread ----
    const int ybase = tw * 16;
    float acc[16];
#pragma unroll
    for (int i = 0; i < 16; ++i) acc[i] = 0.f;

#pragma unroll
    for (int r = 0; r < 36; ++r) {  // rows ybase .. ybase+35 cover taps for 16 outputs
        const float v = hbuf[ybase + r][tx];
#pragma unroll
        for (int yo = 0; yo < 16; ++yo) {
            const int tap = r - yo;
            if (tap >= 0 && tap < KS) acc[yo] += w[tap] * v;
        }
    }

#pragma unroll
    for (int yo = 0; yo < 16; ++yo) {
        outp[(long long)(y0 + ybase + yo) * W + (x0 + tx)] = acc[yo];
    }
}

extern "C" void kernel_launch(void* const* d_in, const int* in_sizes, int n_in,
                              void* d_out, int out_size, void* d_ws, size_t ws_size,
                              hipStream_t stream) {
    const float* x = (const float*)d_in[0];
    const float* k = (const float*)d_in[1];
    float* out = (float*)d_out;
    const int n = in_sizes[0] / (H * W);  // batch*channels = 32
    dim3 grid(W / TILE_X, H / TILE_Y, n);
    gauss_fused<<<grid, dim3(256), 0, stream>>>(x, k, out);
}

// Round 2
// 365.261 us; speedup vs baseline: 1.5209x; 1.5209x over previous
//
#include <hip/hip_runtime.h>

#define H 1024
#define W 1024
#define KS 21
#define RAD 10
#define TX 64
#define TY 128
#define HROWS (TY + 2 * RAD)   // 148
#define LSTRIDE 65             // +1 pad: (row*65+x)%32 spreads rows -> only free 2-way aliasing
#define SEGW 16                // h-outputs per job (register sliding window)
#define NSEG (TX / SEGW)       // 4
#define NJOBS (HROWS * NSEG)   // 592
#define ROWS_PER_WG 32         // phase-2 outputs per thread

// jnp 'reflect' (no edge repeat) for indices in [-(W-1), 2W-2]
__device__ __forceinline__ int reflect1024(int i) {
    return 1023 - abs(1023 - abs(i));
}

__global__ __launch_bounds__(256)
void gauss_fused(const float* __restrict__ in, const float* __restrict__ k2d,
                 float* __restrict__ out) {
    __shared__ float hbuf[HROWS][LSTRIDE];   // 148*65*4 = 38480 B -> 4 blocks/CU
    __shared__ float rw_s[KS];

    const int tid = threadIdx.x;
    const int x0 = blockIdx.x * TX;
    const int y0 = blockIdx.y * TY;
    const long long plane = (long long)blockIdx.z * (long long)(H * W);
    const float* inp = in + plane;

    // separable 1D factor: k2d = outer(r,r), r[i] = k2d[i][c]/sqrt(k2d[c][c])
    if (tid < KS) {
        float c = k2d[RAD * KS + RAD];
        rw_s[tid] = k2d[tid * KS + RAD] / sqrtf(c);
    }
    __syncthreads();

    float w[KS];
#pragma unroll
    for (int j = 0; j < KS; ++j) w[j] = rw_s[j];

    // ---- Phase 1: horizontal conv, register sliding window, 16 outputs/job ----
    // interior blocks: aligned float4 window loads, no x-reflect
    const bool xint = (x0 != 0) && (x0 != W - TX);

#pragma unroll
    for (int k = 0; k < 3; ++k) {
        const int job = tid + 256 * k;
        if (job >= NJOBS) break;
        const int row = job >> 2;    // 0..147
        const int seg = job & 3;
        const int gy = reflect1024(y0 + row - RAD);
        const float* rowp = inp + (long long)gy * W;
        const int xs = x0 + seg * SEGW - RAD;  // first tap x of output 0

        if (xint) {
            // xs-2 is 16B-aligned (x0%64==0, seg*16-12 ≡ 0 mod 4)
            float win[40];
            const float4* p4 = (const float4*)(rowp + (xs - 2));
#pragma unroll
            for (int q = 0; q < 10; ++q) {
                const float4 v = p4[q];
                win[4 * q + 0] = v.x; win[4 * q + 1] = v.y;
                win[4 * q + 2] = v.z; win[4 * q + 3] = v.w;
            }
#pragma unroll
            for (int i = 0; i < SEGW; ++i) {
                float s = 0.f;
#pragma unroll
                for (int j = 0; j < KS; ++j) s += w[j] * win[2 + i + j];
                hbuf[row][seg * SEGW + i] = s;
            }
        } else {
            float win[36];
#pragma unroll
            for (int q = 0; q < 36; ++q) win[q] = rowp[reflect1024(xs + q)];
#pragma unroll
            for (int i = 0; i < SEGW; ++i) {
                float s = 0.f;
#pragma unroll
                for (int j = 0; j < KS; ++j) s += w[j] * win[i + j];
                hbuf[row][seg * SEGW + i] = s;
            }
        }
    }
    __syncthreads();

    // ---- Phase 2: vertical conv, register sliding window, 32 outputs/thread ----
    const int tx = tid & 63;
    const int wg = tid >> 6;            // 0..3
    const int rbase = wg * ROWS_PER_WG; // output rows y0+rbase .. +31

    float acc[ROWS_PER_WG];
#pragma unroll
    for (int i = 0; i < ROWS_PER_WG; ++i) acc[i] = 0.f;

#pragma unroll
    for (int r = 0; r < ROWS_PER_WG + KS - 1; ++r) {  // 52 LDS reads
        const float v = hbuf[rbase + r][tx];
#pragma unroll
        for (int yo = 0; yo < ROWS_PER_WG; ++yo) {
            const int tap = r - yo;           // folds at compile time
            if (tap >= 0 && tap < KS) acc[yo] += w[tap] * v;
        }
    }

    float* outp = out + plane;
#pragma unroll
    for (int yo = 0; yo < ROWS_PER_WG; ++yo) {
        outp[(long long)(y0 + rbase + yo) * W + (x0 + tx)] = acc[yo];
    }
}

extern "C" void kernel_launch(void* const* d_in, const int* in_sizes, int n_in,
                              void* d_out, int out_size, void* d_ws, size_t ws_size,
                              hipStream_t stream) {
    const float* x = (const float*)d_in[0];
    const float* k = (const float*)d_in[1];
    float* out = (float*)d_out;
    const int n = in_sizes[0] / (H * W);  // batch*channels = 32
    dim3 grid(W / TX, H / TY, n);
    gauss_fused<<<grid, dim3(256), 0, stream>>>(x, k, out);
}